// Round 5
// baseline (287.891 us; speedup 1.0000x reference)
//
#include <hip/hip_runtime.h>
#include <hip/hip_bf16.h>
#include <math.h>

#define EPB 64
#define ALPHA 0.17677669529663687f
#define INV_SQRT3 0.57735026918962576f

typedef __attribute__((ext_vector_type(8))) short short8;
typedef __attribute__((ext_vector_type(4))) float f32x4;

__device__ __forceinline__ float silu_f(float x) { return x / (1.0f + __expf(-x)); }

__device__ __forceinline__ unsigned short bf16_rne(float x) {
  unsigned int u = __float_as_uint(x);
  unsigned int r = u + 0x7fffu + ((u >> 16) & 1u);
  return (unsigned short)(r >> 16);
}

// ---------------------------------------------------------------------------
// Prep (known-good R3 version): w2 (64 x 1024 fp32) -> w2t (1024 x 64 bf16).
// ---------------------------------------------------------------------------
__global__ __launch_bounds__(256) void w2t_kernel(const float* __restrict__ w2,
                                                  unsigned short* __restrict__ w2t) {
  __shared__ unsigned short tile[16][260];
  const int t = threadIdx.x;
  const int k0 = (blockIdx.x & 3) * 16;
  const int c0 = (blockIdx.x >> 2) * 256;
  #pragma unroll
  for (int j = 0; j < 16; ++j)
    tile[j][t] = bf16_rne(w2[(size_t)(k0 + j) * 1024 + c0 + t]);
  __syncthreads();
  union { unsigned short s[16]; uint4 q[2]; } pk;
  #pragma unroll
  for (int j = 0; j < 16; ++j) pk.s[j] = tile[j][t];
  uint4* dst = (uint4*)&w2t[(size_t)(c0 + t) * 64 + k0];
  dst[0] = pk.q[0];
  dst[1] = pk.q[1];
}

// ---------------------------------------------------------------------------
// CSR build: per-edge rank within its dst bucket (deg pre-zeroed).
// ---------------------------------------------------------------------------
__global__ __launch_bounds__(256) void count_kernel(const int* __restrict__ eidx,
                                                    int* __restrict__ deg,
                                                    int* __restrict__ rank, int E) {
  const int e = blockIdx.x * 256 + threadIdx.x;
  if (e < E) rank[e] = atomicAdd(&deg[eidx[E + e]], 1);
}

// Single-block exclusive prefix sum over N degrees -> offs[0..N].
__global__ __launch_bounds__(256) void scan_kernel(const int* __restrict__ deg,
                                                   int* __restrict__ offs, int N) {
  __shared__ int sums[256];
  const int t = threadIdx.x;
  const int ch = (N + 255) >> 8;
  const int lo = t * ch;
  const int hi = min(lo + ch, N);
  int s = 0;
  for (int i = lo; i < hi; ++i) s += deg[i];
  sums[t] = s;
  __syncthreads();
  #pragma unroll
  for (int d = 1; d < 256; d <<= 1) {
    int v = (t >= d) ? sums[t - d] : 0;
    __syncthreads();
    sums[t] += v;
    __syncthreads();
  }
  int run = sums[t] - s;
  for (int i = lo; i < hi; ++i) { offs[i] = run; run += deg[i]; }
  if (lo < N && hi == N) offs[N] = run;
}

// ---------------------------------------------------------------------------
// Edge kernel: fused radial-MLP + MFMA tensor-product, symmetric waves.
// Wave mt owns 16 edges and iterates all 4 W-sections; t0..t3 accumulate in
// registers; combine in-register; emit in REFERENCE order (scalar[16] then
// vec[16][3]). B-fragments from w2t (R3 layout/loads). LDS 46 KB.
// ---------------------------------------------------------------------------
__global__ __launch_bounds__(256, 2) void tfn_edge_kernel(
    const float* __restrict__ nf,     // N x 64
    const float* __restrict__ esh,    // E x 4
    const float* __restrict__ emb,    // E x 16
    const float* __restrict__ w1g,    // 16 x 64
    const float* __restrict__ b1g,    // 64
    const unsigned short* __restrict__ w2t, // 1024 x 64 bf16 (transposed)
    const float* __restrict__ b2g,    // 1024
    const int*   __restrict__ eidx,   // 2 x E
    const int*   __restrict__ rank,   // E (posmode)
    const int*   __restrict__ offs,   // N+1 (posmode)
    float* __restrict__ msg,          // E x 64 dst-sorted (posmode)
    float* __restrict__ agg,          // N x 64 pre-zeroed (fallback)
    int E, int posmode)
{
  __shared__ __align__(16) unsigned short hsm[EPB * 72]; // h bf16, stride 72
  __shared__ __align__(16) float embs[EPB * 17];         // fp32, pad 17
  __shared__ __align__(16) float w1s[16 * 64];
  __shared__ __align__(16) float fsT[16 * 72];           // xs       [u][e]
  __shared__ __align__(16) float fbT[16 * 72];           // xv.shv   [u][e]
  __shared__ __align__(16) float fxvT[3 * 16 * 72];      // xv_i     [i][u][e]
  __shared__ __align__(16) float b2s[1024];
  __shared__ float shs_l[EPB];
  __shared__ float shv_l[EPB * 3];
  __shared__ int   pos_l[EPB];

  const int tid = threadIdx.x;
  const int ebase = blockIdx.x * EPB;

  // ---------------- phase 0: stage inputs + factor tables ------------------
  {
    const int e = tid >> 2, p = tid & 3;
    int eg = ebase + e; if (eg >= E) eg = E - 1;

    const float4 em = *(const float4*)&emb[(size_t)eg * 16 + p * 4];
    embs[e * 17 + p * 4 + 0] = em.x;
    embs[e * 17 + p * 4 + 1] = em.y;
    embs[e * 17 + p * 4 + 2] = em.z;
    embs[e * 17 + p * 4 + 3] = em.w;

    if (p == 0) {
      const float4 sh = *(const float4*)&esh[(size_t)eg * 4];
      shs_l[e] = sh.x;
      shv_l[e * 3 + 0] = sh.y; shv_l[e * 3 + 1] = sh.z; shv_l[e * 3 + 2] = sh.w;
      const int dst = eidx[E + eg];
      pos_l[e] = posmode ? (offs[dst] + rank[eg]) : dst;
    }

    const int src = eidx[eg];
    const float* row = nf + (size_t)src * 64;
    const float sv0 = esh[(size_t)eg * 4 + 1];
    const float sv1 = esh[(size_t)eg * 4 + 2];
    const float sv2 = esh[(size_t)eg * 4 + 3];
    #pragma unroll
    for (int uu = 0; uu < 4; ++uu) {
      const int u = p * 4 + uu;
      const float xs = row[u];
      const float x0 = row[16 + u * 3 + 0];
      const float x1 = row[16 + u * 3 + 1];
      const float x2 = row[16 + u * 3 + 2];
      fsT[u * 72 + e] = xs;
      fbT[u * 72 + e] = x0 * sv0 + x1 * sv1 + x2 * sv2;
      fxvT[(0 * 16 + u) * 72 + e] = x0;
      fxvT[(1 * 16 + u) * 72 + e] = x1;
      fxvT[(2 * 16 + u) * 72 + e] = x2;
    }
  }
  {
    const int r = tid >> 4, c4 = (tid & 15) * 4;
    *(float4*)&w1s[r * 64 + c4] = *(const float4*)&w1g[r * 64 + c4];
  }
  *(float4*)&b2s[tid * 4] = *(const float4*)&b2g[tid * 4];
  __syncthreads();

  // ---------------- layer 1: h = silu(emb @ w1 + b1) -> bf16 LDS -----------
  {
    const int e = tid >> 2, p = tid & 3;
    #pragma unroll
    for (int kk = 0; kk < 16; ++kk) {
      const int c = p * 16 + kk;
      float acc = b1g[c];
      #pragma unroll
      for (int j = 0; j < 16; ++j) acc = fmaf(embs[e * 17 + j], w1s[j * 64 + c], acc);
      hsm[e * 72 + c] = bf16_rne(silu_f(acc));
    }
  }
  __syncthreads();

  // ---------------- main loop: wave = 16 edges, all sections ---------------
  const int lane = tid & 63;
  const int mt = tid >> 6;            // wave-uniform M-tile
  const int q = lane >> 4, m = lane & 15;

  union AF { uint4 u4; short8 s8; };
  AF a0, a1;
  a0.u4 = *(const uint4*)&hsm[(mt * 16 + m) * 72 + q * 8];
  a1.u4 = *(const uint4*)&hsm[(mt * 16 + m) * 72 + 32 + q * 8];

  const uint4* w2tq = (const uint4*)w2t;

  float t0a[4] = {0, 0, 0, 0};
  float t1a[4] = {0, 0, 0, 0};
  float t2a[4] = {0, 0, 0, 0};
  float t3a[4][3] = {};

  #pragma unroll 2
  for (int u = 0; u < 16; ++u) {
    const float4 fs4 = *(const float4*)&fsT[u * 72 + mt * 16 + q * 4];
    const float4 fb4 = *(const float4*)&fbT[u * 72 + mt * 16 + q * 4];
    const float4 fx0 = *(const float4*)&fxvT[(0 * 16 + u) * 72 + mt * 16 + q * 4];
    const float4 fx1 = *(const float4*)&fxvT[(1 * 16 + u) * 72 + mt * 16 + q * 4];
    const float4 fx2 = *(const float4*)&fxvT[(2 * 16 + u) * 72 + mt * 16 + q * 4];
    const float fs[4] = {fs4.x, fs4.y, fs4.z, fs4.w};
    const float fb[4] = {fb4.x, fb4.y, fb4.z, fb4.w};
    const float f0[4] = {fx0.x, fx0.y, fx0.z, fx0.w};
    const float f1[4] = {fx1.x, fx1.y, fx1.z, fx1.w};
    const float f2[4] = {fx2.x, fx2.y, fx2.z, fx2.w};

    #pragma unroll
    for (int sec = 0; sec < 4; ++sec) {
      const int col = sec * 256 + u * 16 + m;
      AF b0, b1;
      const uint4* bp = w2tq + (size_t)col * 8 + q;     // R3-proven B load
      b0.u4 = bp[0];
      b1.u4 = bp[4];
      const float b2v = b2s[col];

      f32x4 c = {0.0f, 0.0f, 0.0f, 0.0f};
      c = __builtin_amdgcn_mfma_f32_16x16x32_bf16(a0.s8, b0.s8, c, 0, 0, 0);
      c = __builtin_amdgcn_mfma_f32_16x16x32_bf16(a1.s8, b1.s8, c, 0, 0, 0);

      if (sec == 0) {
        #pragma unroll
        for (int r = 0; r < 4; ++r) t0a[r] = fmaf(fs[r], c[r] + b2v, t0a[r]);
      } else if (sec == 1) {
        #pragma unroll
        for (int r = 0; r < 4; ++r) t2a[r] = fmaf(fs[r], c[r] + b2v, t2a[r]);
      } else if (sec == 2) {
        #pragma unroll
        for (int r = 0; r < 4; ++r) {
          const float tp = c[r] + b2v;
          t3a[r][0] = fmaf(f0[r], tp, t3a[r][0]);
          t3a[r][1] = fmaf(f1[r], tp, t3a[r][1]);
          t3a[r][2] = fmaf(f2[r], tp, t3a[r][2]);
        }
      } else {
        #pragma unroll
        for (int r = 0; r < 4; ++r) t1a[r] = fmaf(fb[r], c[r] + b2v, t1a[r]);
      }
    }
  }

  // ---------------- in-register combine + emit (reference order) -----------
  #pragma unroll
  for (int r = 0; r < 4; ++r) {
    const int e_row = mt * 16 + q * 4 + r;
    if (ebase + e_row < E) {
      const float shs_e = shs_l[e_row];
      const float sv0 = shv_l[e_row * 3 + 0];
      const float sv1 = shv_l[e_row * 3 + 1];
      const float sv2 = shv_l[e_row * 3 + 2];
      const float s  = ALPHA * (t0a[r] * shs_e + INV_SQRT3 * t1a[r]);
      const float v0 = ALPHA * (t2a[r] * sv0 + t3a[r][0] * shs_e);
      const float v1 = ALPHA * (t2a[r] * sv1 + t3a[r][1] * shs_e);
      const float v2 = ALPHA * (t2a[r] * sv2 + t3a[r][2] * shs_e);
      if (posmode) {
        float* mrow = msg + (size_t)pos_l[e_row] * 64;
        mrow[m] = s;                       // scalar channel v=m
        mrow[16 + m * 3 + 0] = v0;         // vector channel (v=m, i)
        mrow[16 + m * 3 + 1] = v1;
        mrow[16 + m * 3 + 2] = v2;
      } else {
        float* arow = agg + (size_t)pos_l[e_row] * 64;
        atomicAdd(&arow[m], s);
        atomicAdd(&arow[16 + m * 3 + 0], v0);
        atomicAdd(&arow[16 + m * 3 + 1], v1);
        atomicAdd(&arow[16 + m * 3 + 2], v2);
      }
    }
  }
}

// ---------------------------------------------------------------------------
// Fused aggregation + node transform. Block = 4 nodes.
// Phase A: wave-per-node contiguous slab sum (msg is in reference order).
// Phase B: thread-per-(node,component) linear + gate + residual.
// ---------------------------------------------------------------------------
__global__ __launch_bounds__(256) void tfn_agg_node_kernel(
    const float* __restrict__ msg, const int* __restrict__ offs,
    const float* __restrict__ nf, const float* __restrict__ lw0,
    const float* __restrict__ lw1, float* __restrict__ out, int N)
{
  __shared__ float ag[4 * 68];
  __shared__ float w0s[256], w1s[256];
  const int t = threadIdx.x;
  w0s[t] = lw0[t];
  w1s[t] = lw1[t];

  const int n0 = blockIdx.x * 4;
  {
    const int w = t >> 6, lane = t & 63;
    const int n = n0 + w;
    if (n < N) {
      const int s = offs[n], e = offs[n + 1];
      float acc = 0.0f;
      int j = s;
      for (; j + 1 < e; j += 2)
        acc += msg[(size_t)j * 64 + lane] + msg[(size_t)(j + 1) * 64 + lane];
      if (j < e) acc += msg[(size_t)j * 64 + lane];
      ag[w * 68 + lane] = acc;     // reference order: [0..15]=s, [16+u*3+i]=v
    }
  }
  __syncthreads();
  {
    const int node = t >> 6, c = t & 63;
    const int n = n0 + node;
    if (n >= N) return;
    const float* a = &ag[node * 68];
    float val;
    if (c < 16) {
      float accv = 0.0f;
      #pragma unroll
      for (int u = 0; u < 16; ++u) accv = fmaf(a[u], w0s[u * 16 + c], accv);
      const float ts = 0.25f * accv;
      const float ns = fabsf(ts);
      const float g = (ns / (1.0f + __expf(-ns))) / (ns + 1e-8f);
      val = ts * g;
    } else {
      const int cc = c - 16;
      const int v = cc / 3, i = cc - v * 3;
      float a0 = 0.0f, a1 = 0.0f, a2 = 0.0f;
      #pragma unroll
      for (int u = 0; u < 16; ++u) {
        const float w = w1s[u * 16 + v];
        a0 = fmaf(a[16 + u * 3 + 0], w, a0);
        a1 = fmaf(a[16 + u * 3 + 1], w, a1);
        a2 = fmaf(a[16 + u * 3 + 2], w, a2);
      }
      a0 *= 0.25f; a1 *= 0.25f; a2 *= 0.25f;
      const float nv = sqrtf(a0 * a0 + a1 * a1 + a2 * a2);
      const float g = (nv / (1.0f + __expf(-nv))) / (nv + 1e-8f);
      val = ((i == 0) ? a0 : (i == 1) ? a1 : a2) * g;
    }
    out[(size_t)n * 64 + c] = nf[(size_t)n * 64 + c] + val;
  }
}

// ---------------------------------------------------------------------------
// Fallback node kernel (atomic path only).
// ---------------------------------------------------------------------------
__global__ __launch_bounds__(256) void tfn_node_kernel(
    const float* __restrict__ nf,
    const float* __restrict__ lw0,
    const float* __restrict__ lw1,
    float* __restrict__ out, int N)
{
  __shared__ float w0s[256], w1s[256];
  const int tid = threadIdx.x;
  w0s[tid] = lw0[tid];
  w1s[tid] = lw1[tid];
  __syncthreads();

  const int n = blockIdx.x * 256 + tid;
  if (n >= N) return;

  float* rowp = out + (size_t)n * 64;
  float as[16], av[16][3];
  #pragma unroll
  for (int u = 0; u < 16; ++u) as[u] = rowp[u];
  #pragma unroll
  for (int u = 0; u < 16; ++u) {
    av[u][0] = rowp[16 + u * 3 + 0];
    av[u][1] = rowp[16 + u * 3 + 1];
    av[u][2] = rowp[16 + u * 3 + 2];
  }
  const float* nfr = nf + (size_t)n * 64;
  float res[64];

  #pragma unroll
  for (int v = 0; v < 16; ++v) {
    float acc = 0.0f;
    #pragma unroll
    for (int u = 0; u < 16; ++u) acc = fmaf(as[u], w0s[u * 16 + v], acc);
    const float ts = 0.25f * acc;
    const float ns = fabsf(ts);
    const float g = (ns / (1.0f + __expf(-ns))) / (ns + 1e-8f);
    res[v] = nfr[v] + ts * g;
  }
  #pragma unroll
  for (int v = 0; v < 16; ++v) {
    float a0 = 0.0f, a1 = 0.0f, a2 = 0.0f;
    #pragma unroll
    for (int u = 0; u < 16; ++u) {
      const float w = w1s[u * 16 + v];
      a0 = fmaf(av[u][0], w, a0);
      a1 = fmaf(av[u][1], w, a1);
      a2 = fmaf(av[u][2], w, a2);
    }
    a0 *= 0.25f; a1 *= 0.25f; a2 *= 0.25f;
    const float nv = sqrtf(a0 * a0 + a1 * a1 + a2 * a2);
    const float g = (nv / (1.0f + __expf(-nv))) / (nv + 1e-8f);
    res[16 + v * 3 + 0] = nfr[16 + v * 3 + 0] + a0 * g;
    res[16 + v * 3 + 1] = nfr[16 + v * 3 + 1] + a1 * g;
    res[16 + v * 3 + 2] = nfr[16 + v * 3 + 2] + a2 * g;
  }
  #pragma unroll
  for (int o = 0; o < 64; o += 4) {
    *(float4*)&rowp[o] = make_float4(res[o], res[o + 1], res[o + 2], res[o + 3]);
  }
}

extern "C" void kernel_launch(void* const* d_in, const int* in_sizes, int n_in,
                              void* d_out, int out_size, void* d_ws, size_t ws_size,
                              hipStream_t stream) {
  const float* nf  = (const float*)d_in[0];
  const float* esh = (const float*)d_in[1];
  const float* emb = (const float*)d_in[2];
  const float* w1  = (const float*)d_in[3];
  const float* b1  = (const float*)d_in[4];
  const float* w2  = (const float*)d_in[5];
  const float* b2  = (const float*)d_in[6];
  const float* lw0 = (const float*)d_in[7];
  const float* lw1 = (const float*)d_in[8];
  const int*   eix = (const int*)d_in[9];

  const int N = in_sizes[0] / 64;
  const int E = in_sizes[9] / 2;
  float* out = (float*)d_out;

  // workspace layout
  char* ws = (char*)d_ws;
  const size_t o_w2t  = 0;                       // 1024 x 64 bf16 = 128 KB
  const size_t o_deg  = 131072;
  const size_t o_offs = o_deg  + (((size_t)N * 4 + 15) & ~(size_t)15);
  const size_t o_rank = o_offs + (((size_t)(N + 1) * 4 + 15) & ~(size_t)15);
  const size_t o_msg  = (o_rank + (size_t)E * 4 + 255) & ~(size_t)255;
  const size_t need   = o_msg + (size_t)E * 256;
  const int posmode = (ws_size >= need) ? 1 : 0;

  unsigned short* w2t = (unsigned short*)(ws + o_w2t);
  int*   deg  = (int*)(ws + o_deg);
  int*   offs = (int*)(ws + o_offs);
  int*   rankp = (int*)(ws + o_rank);
  float* msg  = (float*)(ws + o_msg);

  w2t_kernel<<<dim3(16), dim3(256), 0, stream>>>(w2, w2t);

  const int eblocks = (E + EPB - 1) / EPB;

  if (posmode) {
    hipMemsetAsync(deg, 0, (size_t)N * 4, stream);
    count_kernel<<<dim3((E + 255) / 256), dim3(256), 0, stream>>>(eix, deg, rankp, E);
    scan_kernel<<<dim3(1), dim3(256), 0, stream>>>(deg, offs, N);
    tfn_edge_kernel<<<dim3(eblocks), dim3(256), 0, stream>>>(
        nf, esh, emb, w1, b1, w2t, b2, eix, rankp, offs, msg, out, E, 1);
    tfn_agg_node_kernel<<<dim3((N + 3) / 4), dim3(256), 0, stream>>>(
        msg, offs, nf, lw0, lw1, out, N);
  } else {
    hipMemsetAsync(out, 0, (size_t)out_size * sizeof(float), stream);
    tfn_edge_kernel<<<dim3(eblocks), dim3(256), 0, stream>>>(
        nf, esh, emb, w1, b1, w2t, b2, eix, nullptr, nullptr, nullptr, out, E, 0);
    tfn_node_kernel<<<dim3((N + 255) / 256), dim3(256), 0, stream>>>(nf, lw0, lw1, out, N);
  }
}

// Round 6
// 188.919 us; speedup vs baseline: 1.5239x; 1.5239x over previous
//
#include <hip/hip_runtime.h>
#include <hip/hip_bf16.h>
#include <math.h>

#define EPB 64
#define ALPHA 0.17677669529663687f
#define INV_SQRT3 0.57735026918962576f

typedef __attribute__((ext_vector_type(8))) short short8;
typedef __attribute__((ext_vector_type(4))) float f32x4;

__device__ __forceinline__ float silu_f(float x) { return x / (1.0f + __expf(-x)); }

__device__ __forceinline__ unsigned short bf16_rne(float x) {
  unsigned int u = __float_as_uint(x);
  unsigned int r = u + 0x7fffu + ((u >> 16) & 1u);
  return (unsigned short)(r >> 16);
}

// load 4 consecutive bf16 (8B-aligned) from LDS -> 4 floats
__device__ __forceinline__ void ld4bf(float* d, const unsigned short* s) {
  const uint2 t = *(const uint2*)s;
  d[0] = __uint_as_float(t.x << 16);
  d[1] = __uint_as_float(t.x & 0xffff0000u);
  d[2] = __uint_as_float(t.y << 16);
  d[3] = __uint_as_float(t.y & 0xffff0000u);
}

// ---------------------------------------------------------------------------
// Merged prep: blocks 0..15 transpose w2 -> w2t (R3-proven code);
// blocks 16.. do the CSR count (rank = atomicAdd(deg[dst])).
// ---------------------------------------------------------------------------
__global__ __launch_bounds__(256) void prep_kernel(const float* __restrict__ w2,
                                                   unsigned short* __restrict__ w2t,
                                                   const int* __restrict__ eidx,
                                                   int* __restrict__ deg,
                                                   int* __restrict__ rank, int E) {
  if (blockIdx.x < 16) {
    __shared__ unsigned short tile[16][260];
    const int t = threadIdx.x;
    const int k0 = (blockIdx.x & 3) * 16;
    const int c0 = (blockIdx.x >> 2) * 256;
    #pragma unroll
    for (int j = 0; j < 16; ++j)
      tile[j][t] = bf16_rne(w2[(size_t)(k0 + j) * 1024 + c0 + t]);
    __syncthreads();
    union { unsigned short s[16]; uint4 q[2]; } pk;
    #pragma unroll
    for (int j = 0; j < 16; ++j) pk.s[j] = tile[j][t];
    uint4* dst = (uint4*)&w2t[(size_t)(c0 + t) * 64 + k0];
    dst[0] = pk.q[0];
    dst[1] = pk.q[1];
  } else {
    const int e = (blockIdx.x - 16) * 256 + threadIdx.x;
    if (e < E) rank[e] = atomicAdd(&deg[eidx[E + e]], 1);
  }
}

// Single-block exclusive prefix sum over N degrees -> offs[0..N].
__global__ __launch_bounds__(256) void scan_kernel(const int* __restrict__ deg,
                                                   int* __restrict__ offs, int N) {
  __shared__ int sums[256];
  const int t = threadIdx.x;
  const int ch = (N + 255) >> 8;
  const int lo = t * ch;
  const int hi = min(lo + ch, N);
  int s = 0;
  for (int i = lo; i < hi; ++i) s += deg[i];
  sums[t] = s;
  __syncthreads();
  #pragma unroll
  for (int d = 1; d < 256; d <<= 1) {
    int v = (t >= d) ? sums[t - d] : 0;
    __syncthreads();
    sums[t] += v;
    __syncthreads();
  }
  int run = sums[t] - s;
  for (int i = lo; i < hi; ++i) { offs[i] = run; run += deg[i]; }
  if (lo < N && hi == N) offs[N] = run;
}

// ---------------------------------------------------------------------------
// Edge kernel: R3 structure (wave = one W-section, 4 M-tiles -> B-reuse x4,
// plain-store t-flush) + bf16 factor tables + 1-deep B prefetch + coalesced
// combine. LDS 51 KB -> 3 blocks/CU.
// ---------------------------------------------------------------------------
__global__ __launch_bounds__(256, 3) void tfn_edge_kernel(
    const float* __restrict__ nf,     // N x 64
    const float* __restrict__ esh,    // E x 4
    const float* __restrict__ emb,    // E x 16
    const float* __restrict__ w1g,    // 16 x 64
    const float* __restrict__ b1g,    // 64
    const unsigned short* __restrict__ w2t, // 1024 x 64 bf16 (transposed)
    const float* __restrict__ b2g,    // 1024
    const int*   __restrict__ eidx,   // 2 x E
    const int*   __restrict__ rank,   // E (posmode)
    const int*   __restrict__ offs,   // N+1 (posmode)
    float* __restrict__ msg,          // E x 64 dst-sorted (posmode)
    float* __restrict__ agg,          // N x 64 pre-zeroed (fallback)
    int E, int posmode)
{
  __shared__ __align__(16) unsigned short hsm[EPB * 72];  // h bf16, stride 72
  __shared__ __align__(16) float t01[2 * 1088];           // t0 | t1 (overlay: embs,w1s)
  __shared__ __align__(16) float t2s[1088];
  __shared__ __align__(16) float t3s[3 * 1088];           // [i][e*17+v]
  __shared__ __align__(16) unsigned short fsT[16 * 72];   // xs     bf16 [u][e]
  __shared__ __align__(16) unsigned short fbT[16 * 72];   // xv.shv bf16 [u][e]
  __shared__ __align__(16) unsigned short fxvT[48 * 72];  // xv_i   bf16 [i*16+u][e]
  __shared__ __align__(16) float b2s[1024];
  __shared__ float shs_l[EPB];
  __shared__ float shv_l[EPB * 3];
  __shared__ int   pos_l[EPB];

  const int tid = threadIdx.x;
  const int ebase = blockIdx.x * EPB;

  float* embs = t01;          // overlay: [64][17], dead after layer 1
  float* w1s  = t01 + 1088;   // overlay: [16][64]

  // ---------------- phase 0: stage inputs + factor tables ------------------
  {
    const int e = tid >> 2, p = tid & 3;
    int eg = ebase + e; if (eg >= E) eg = E - 1;

    const float4 em = *(const float4*)&emb[(size_t)eg * 16 + p * 4];
    embs[e * 17 + p * 4 + 0] = em.x;
    embs[e * 17 + p * 4 + 1] = em.y;
    embs[e * 17 + p * 4 + 2] = em.z;
    embs[e * 17 + p * 4 + 3] = em.w;

    const float4 sh = *(const float4*)&esh[(size_t)eg * 4];
    if (p == 0) {
      shs_l[e] = sh.x;
      shv_l[e * 3 + 0] = sh.y; shv_l[e * 3 + 1] = sh.z; shv_l[e * 3 + 2] = sh.w;
      const int dst = eidx[E + eg];
      pos_l[e] = posmode ? (offs[dst] + rank[eg]) : dst;
    }

    const int src = eidx[eg];
    const float4* row4 = (const float4*)(nf + (size_t)src * 64);
    const float4 xs4 = row4[p];                 // xs for u = p*4..p*4+3
    const float4 va  = row4[4 + p * 3 + 0];     // xv flat [p*12 .. p*12+11]
    const float4 vb  = row4[4 + p * 3 + 1];
    const float4 vc  = row4[4 + p * 3 + 2];
    const float xsr[4] = {xs4.x, xs4.y, xs4.z, xs4.w};
    const float xvf[12] = {va.x, va.y, va.z, va.w, vb.x, vb.y, vb.z, vb.w,
                           vc.x, vc.y, vc.z, vc.w};
    #pragma unroll
    for (int uu = 0; uu < 4; ++uu) {
      const int u = p * 4 + uu;
      const float x0 = xvf[uu * 3 + 0];
      const float x1 = xvf[uu * 3 + 1];
      const float x2 = xvf[uu * 3 + 2];
      fsT[u * 72 + e] = bf16_rne(xsr[uu]);
      fbT[u * 72 + e] = bf16_rne(x0 * sh.y + x1 * sh.z + x2 * sh.w);
      fxvT[(0 * 16 + u) * 72 + e] = bf16_rne(x0);
      fxvT[(1 * 16 + u) * 72 + e] = bf16_rne(x1);
      fxvT[(2 * 16 + u) * 72 + e] = bf16_rne(x2);
    }
  }
  {
    const int r = tid >> 4, c4 = (tid & 15) * 4;
    *(float4*)&w1s[r * 64 + c4] = *(const float4*)&w1g[r * 64 + c4];
  }
  *(float4*)&b2s[tid * 4] = *(const float4*)&b2g[tid * 4];
  __syncthreads();

  // ---------------- layer 1: h = silu(emb @ w1 + b1) -> bf16 LDS -----------
  {
    const int e = tid >> 2, p = tid & 3;
    #pragma unroll
    for (int kk = 0; kk < 16; ++kk) {
      const int c = p * 16 + kk;
      float acc = b1g[c];
      #pragma unroll
      for (int j = 0; j < 16; ++j) acc = fmaf(embs[e * 17 + j], w1s[j * 64 + c], acc);
      hsm[e * 72 + c] = bf16_rne(silu_f(acc));
    }
  }
  __syncthreads();

  // ---------------- main loop: wave = section, 4 M-tiles, B prefetch -------
  const int lane = tid & 63;
  const int sec  = tid >> 6;           // wave-uniform
  const int q = lane >> 4, m = lane & 15;

  union AF { uint4 u4; short8 s8; };
  AF afr[4][2];
  #pragma unroll
  for (int mt = 0; mt < 4; ++mt)
    #pragma unroll
    for (int ks = 0; ks < 2; ++ks)
      afr[mt][ks].u4 = *(const uint4*)&hsm[(mt * 16 + m) * 72 + ks * 32 + q * 8];

  const unsigned short* ftab = (sec == 3) ? fbT : fsT;
  const uint4* w2tq = (const uint4*)w2t;
  const uint4* bp = w2tq + ((size_t)(sec * 256 + m)) * 8 + q;  // col(u) = base + u*16

  float accA[4][4] = {};
  float accB[4][4] = {};
  float accC[4][4] = {};

  AF b0v, b1v;
  b0v.u4 = bp[0];
  b1v.u4 = bp[4];

  #pragma unroll 2
  for (int u = 0; u < 16; ++u) {
    AF n0, n1;
    if (u < 15) {                       // prefetch next u's B pair
      n0.u4 = bp[(u + 1) * 128];
      n1.u4 = bp[(u + 1) * 128 + 4];
    }
    const float b2v = b2s[sec * 256 + u * 16 + m];

    #pragma unroll
    for (int mt = 0; mt < 4; ++mt) {
      f32x4 c = {0.0f, 0.0f, 0.0f, 0.0f};
      c = __builtin_amdgcn_mfma_f32_16x16x32_bf16(afr[mt][0].s8, b0v.s8, c, 0, 0, 0);
      c = __builtin_amdgcn_mfma_f32_16x16x32_bf16(afr[mt][1].s8, b1v.s8, c, 0, 0, 0);

      const int fo = mt * 16 + q * 4;
      float fA[4], fB[4], fC[4];
      if (sec == 2) {
        ld4bf(fA, &fxvT[(0 * 16 + u) * 72 + fo]);
        ld4bf(fB, &fxvT[(1 * 16 + u) * 72 + fo]);
        ld4bf(fC, &fxvT[(2 * 16 + u) * 72 + fo]);
        #pragma unroll
        for (int r = 0; r < 4; ++r) {
          const float tp = c[r] + b2v;
          accA[mt][r] = fmaf(fA[r], tp, accA[mt][r]);
          accB[mt][r] = fmaf(fB[r], tp, accB[mt][r]);
          accC[mt][r] = fmaf(fC[r], tp, accC[mt][r]);
        }
      } else {
        ld4bf(fA, &ftab[u * 72 + fo]);
        #pragma unroll
        for (int r = 0; r < 4; ++r)
          accA[mt][r] = fmaf(fA[r], c[r] + b2v, accA[mt][r]);
      }
    }
    b0v = n0;
    b1v = n1;
  }

  // ---------------- flush wave partials to LDS (plain stores) --------------
  #pragma unroll
  for (int mt = 0; mt < 4; ++mt)
    #pragma unroll
    for (int r = 0; r < 4; ++r) {
      const int e = mt * 16 + q * 4 + r;
      if (sec == 0)      t01[e * 17 + m]        = accA[mt][r] * shs_l[e];
      else if (sec == 1) t2s[e * 17 + m]        = accA[mt][r];
      else if (sec == 3) t01[1088 + e * 17 + m] = accA[mt][r];
      else {
        const float s = shs_l[e];
        t3s[0 * 1088 + e * 17 + m] = accA[mt][r] * s;
        t3s[1 * 1088 + e * 17 + m] = accB[mt][r] * s;
        t3s[2 * 1088 + e * 17 + m] = accC[mt][r] * s;
      }
    }
  __syncthreads();

  // ---------------- combine + emit, coalesced per-edge rows ----------------
  {
    const int w = tid >> 6, lc = tid & 63;
    const int cc = lc - 16;
    const int v  = cc / 3;            // only used when lc >= 16
    const int i3 = cc - v * 3;
    #pragma unroll 1
    for (int t8 = 0; t8 < 16; ++t8) {
      const int e = w * 16 + t8;
      if (ebase + e < E) {
        float val;
        if (lc < 16) {
          val = ALPHA * (t01[e * 17 + lc] + INV_SQRT3 * t01[1088 + e * 17 + lc]);
        } else {
          val = ALPHA * (t2s[e * 17 + v] * shv_l[e * 3 + i3] + t3s[i3 * 1088 + e * 17 + v]);
        }
        if (posmode) msg[(size_t)pos_l[e] * 64 + lc] = val;
        else         atomicAdd(&agg[(size_t)pos_l[e] * 64 + lc], val);
      }
    }
  }
}

// ---------------------------------------------------------------------------
// Fused aggregation + node transform (R5-proven). Block = 4 nodes.
// ---------------------------------------------------------------------------
__global__ __launch_bounds__(256) void tfn_agg_node_kernel(
    const float* __restrict__ msg, const int* __restrict__ offs,
    const float* __restrict__ nf, const float* __restrict__ lw0,
    const float* __restrict__ lw1, float* __restrict__ out, int N)
{
  __shared__ float ag[4 * 68];
  __shared__ float w0s[256], w1s[256];
  const int t = threadIdx.x;
  w0s[t] = lw0[t];
  w1s[t] = lw1[t];

  const int n0 = blockIdx.x * 4;
  {
    const int w = t >> 6, lane = t & 63;
    const int n = n0 + w;
    if (n < N) {
      const int s = offs[n], e = offs[n + 1];
      float a0 = 0.0f, a1 = 0.0f, a2 = 0.0f, a3 = 0.0f;
      int j = s;
      for (; j + 3 < e; j += 4) {
        a0 += msg[(size_t)(j + 0) * 64 + lane];
        a1 += msg[(size_t)(j + 1) * 64 + lane];
        a2 += msg[(size_t)(j + 2) * 64 + lane];
        a3 += msg[(size_t)(j + 3) * 64 + lane];
      }
      for (; j < e; ++j) a0 += msg[(size_t)j * 64 + lane];
      ag[w * 68 + lane] = (a0 + a1) + (a2 + a3);
    }
  }
  __syncthreads();
  {
    const int node = t >> 6, c = t & 63;
    const int n = n0 + node;
    if (n >= N) return;
    const float* a = &ag[node * 68];
    float val;
    if (c < 16) {
      float accv = 0.0f;
      #pragma unroll
      for (int u = 0; u < 16; ++u) accv = fmaf(a[u], w0s[u * 16 + c], accv);
      const float ts = 0.25f * accv;
      const float ns = fabsf(ts);
      const float g = (ns / (1.0f + __expf(-ns))) / (ns + 1e-8f);
      val = ts * g;
    } else {
      const int cc = c - 16;
      const int v = cc / 3, i = cc - v * 3;
      float a0 = 0.0f, a1 = 0.0f, a2 = 0.0f;
      #pragma unroll
      for (int u = 0; u < 16; ++u) {
        const float w = w1s[u * 16 + v];
        a0 = fmaf(a[16 + u * 3 + 0], w, a0);
        a1 = fmaf(a[16 + u * 3 + 1], w, a1);
        a2 = fmaf(a[16 + u * 3 + 2], w, a2);
      }
      a0 *= 0.25f; a1 *= 0.25f; a2 *= 0.25f;
      const float nv = sqrtf(a0 * a0 + a1 * a1 + a2 * a2);
      const float g = (nv / (1.0f + __expf(-nv))) / (nv + 1e-8f);
      val = ((i == 0) ? a0 : (i == 1) ? a1 : a2) * g;
    }
    out[(size_t)n * 64 + c] = nf[(size_t)n * 64 + c] + val;
  }
}

// ---------------------------------------------------------------------------
// Fallback node kernel (atomic path only).
// ---------------------------------------------------------------------------
__global__ __launch_bounds__(256) void tfn_node_kernel(
    const float* __restrict__ nf,
    const float* __restrict__ lw0,
    const float* __restrict__ lw1,
    float* __restrict__ out, int N)
{
  __shared__ float w0s[256], w1s[256];
  const int tid = threadIdx.x;
  w0s[tid] = lw0[tid];
  w1s[tid] = lw1[tid];
  __syncthreads();

  const int n = blockIdx.x * 256 + tid;
  if (n >= N) return;

  float* rowp = out + (size_t)n * 64;
  float as[16], av[16][3];
  #pragma unroll
  for (int u = 0; u < 16; ++u) as[u] = rowp[u];
  #pragma unroll
  for (int u = 0; u < 16; ++u) {
    av[u][0] = rowp[16 + u * 3 + 0];
    av[u][1] = rowp[16 + u * 3 + 1];
    av[u][2] = rowp[16 + u * 3 + 2];
  }
  const float* nfr = nf + (size_t)n * 64;
  float res[64];

  #pragma unroll
  for (int v = 0; v < 16; ++v) {
    float acc = 0.0f;
    #pragma unroll
    for (int u = 0; u < 16; ++u) acc = fmaf(as[u], w0s[u * 16 + v], acc);
    const float ts = 0.25f * acc;
    const float ns = fabsf(ts);
    const float g = (ns / (1.0f + __expf(-ns))) / (ns + 1e-8f);
    res[v] = nfr[v] + ts * g;
  }
  #pragma unroll
  for (int v = 0; v < 16; ++v) {
    float a0 = 0.0f, a1 = 0.0f, a2 = 0.0f;
    #pragma unroll
    for (int u = 0; u < 16; ++u) {
      const float w = w1s[u * 16 + v];
      a0 = fmaf(av[u][0], w, a0);
      a1 = fmaf(av[u][1], w, a1);
      a2 = fmaf(av[u][2], w, a2);
    }
    a0 *= 0.25f; a1 *= 0.25f; a2 *= 0.25f;
    const float nv = sqrtf(a0 * a0 + a1 * a1 + a2 * a2);
    const float g = (nv / (1.0f + __expf(-nv))) / (nv + 1e-8f);
    res[16 + v * 3 + 0] = nfr[16 + v * 3 + 0] + a0 * g;
    res[16 + v * 3 + 1] = nfr[16 + v * 3 + 1] + a1 * g;
    res[16 + v * 3 + 2] = nfr[16 + v * 3 + 2] + a2 * g;
  }
  #pragma unroll
  for (int o = 0; o < 64; o += 4) {
    *(float4*)&rowp[o] = make_float4(res[o], res[o + 1], res[o + 2], res[o + 3]);
  }
}

extern "C" void kernel_launch(void* const* d_in, const int* in_sizes, int n_in,
                              void* d_out, int out_size, void* d_ws, size_t ws_size,
                              hipStream_t stream) {
  const float* nf  = (const float*)d_in[0];
  const float* esh = (const float*)d_in[1];
  const float* emb = (const float*)d_in[2];
  const float* w1  = (const float*)d_in[3];
  const float* b1  = (const float*)d_in[4];
  const float* w2  = (const float*)d_in[5];
  const float* b2  = (const float*)d_in[6];
  const float* lw0 = (const float*)d_in[7];
  const float* lw1 = (const float*)d_in[8];
  const int*   eix = (const int*)d_in[9];

  const int N = in_sizes[0] / 64;
  const int E = in_sizes[9] / 2;
  float* out = (float*)d_out;

  // workspace layout
  char* ws = (char*)d_ws;
  const size_t o_w2t  = 0;                       // 1024 x 64 bf16 = 128 KB
  const size_t o_deg  = 131072;
  const size_t o_offs = o_deg  + (((size_t)N * 4 + 15) & ~(size_t)15);
  const size_t o_rank = o_offs + (((size_t)(N + 1) * 4 + 15) & ~(size_t)15);
  const size_t o_msg  = (o_rank + (size_t)E * 4 + 255) & ~(size_t)255;
  const size_t need   = o_msg + (size_t)E * 256;
  const int posmode = (ws_size >= need) ? 1 : 0;

  unsigned short* w2t = (unsigned short*)(ws + o_w2t);
  int*   deg  = (int*)(ws + o_deg);
  int*   offs = (int*)(ws + o_offs);
  int*   rankp = (int*)(ws + o_rank);
  float* msg  = (float*)(ws + o_msg);

  const int eblocks = (E + EPB - 1) / EPB;

  if (posmode) {
    hipMemsetAsync(deg, 0, (size_t)N * 4, stream);
    prep_kernel<<<dim3(16 + (E + 255) / 256), dim3(256), 0, stream>>>(
        w2, w2t, eix, deg, rankp, E);
    scan_kernel<<<dim3(1), dim3(256), 0, stream>>>(deg, offs, N);
    tfn_edge_kernel<<<dim3(eblocks), dim3(256), 0, stream>>>(
        nf, esh, emb, w1, b1, w2t, b2, eix, rankp, offs, msg, out, E, 1);
    tfn_agg_node_kernel<<<dim3((N + 3) / 4), dim3(256), 0, stream>>>(
        msg, offs, nf, lw0, lw1, out, N);
  } else {
    prep_kernel<<<dim3(16), dim3(256), 0, stream>>>(w2, w2t, eix, nullptr, nullptr, 0);
    hipMemsetAsync(out, 0, (size_t)out_size * sizeof(float), stream);
    tfn_edge_kernel<<<dim3(eblocks), dim3(256), 0, stream>>>(
        nf, esh, emb, w1, b1, w2t, b2, eix, nullptr, nullptr, nullptr, out, E, 0);
    tfn_node_kernel<<<dim3((N + 255) / 256), dim3(256), 0, stream>>>(nf, lw0, lw1, out, N);
  }
}